// Round 2
// baseline (333.743 us; speedup 1.0000x reference)
//
#include <hip/hip_runtime.h>
#include <hip/hip_bf16.h>

#define Bn 2
#define Sn 1024
#define Dn 2048
#define Hn 16
#define HKVn 4
#define HDn 128

typedef __attribute__((ext_vector_type(8))) short s8v;
typedef __attribute__((ext_vector_type(4))) float f4v;
typedef __hip_bfloat16 bf16;

static __device__ __forceinline__ unsigned short f2b_bits(float f) {
  bf16 h = __float2bfloat16(f);
  return __builtin_bit_cast(unsigned short, h);
}

// ---------------- mask normalize (detect int32 vs byte bool) ----------------
__global__ void mask_norm(const void* __restrict__ mraw, unsigned char* __restrict__ m8, int n) {
  __shared__ int bytemode;
  if (threadIdx.x == 0) bytemode = 0;
  __syncthreads();
  const unsigned int* mi = (const unsigned int*)mraw;
  int local = 0;
  for (int t = threadIdx.x; t < n / 4; t += blockDim.x)
    if (mi[t] > 1u) local = 1;
  if (local) atomicOr(&bytemode, 1);
  __syncthreads();
  const int bm = bytemode;
  const unsigned char* mb = (const unsigned char*)mraw;
  for (int t = threadIdx.x; t < n; t += blockDim.x)
    m8[t] = bm ? (mb[t] ? 1 : 0) : (mi[t] != 0u ? 1 : 0);
}

// ---------------- fp32 -> bf16 convert ----------------
__global__ void cvt_bf16(const float* __restrict__ src, bf16* __restrict__ dst, int n4) {
  int stride = gridDim.x * blockDim.x;
  for (int i = blockIdx.x * blockDim.x + threadIdx.x; i < n4; i += stride) {
    float4 v = reinterpret_cast<const float4*>(src)[i];
    ushort4 o;
    o.x = f2b_bits(v.x); o.y = f2b_bits(v.y); o.z = f2b_bits(v.z); o.w = f2b_bits(v.w);
    reinterpret_cast<ushort4*>(dst)[i] = o;
  }
}

// ---------------- fp32 (K,N) -> bf16 (N,K) transpose ----------------
__global__ void transpose_w(const float* __restrict__ src, bf16* __restrict__ dst, int K, int N) {
  __shared__ float tile[32][33];
  int bx = blockIdx.x * 32;  // n
  int by = blockIdx.y * 32;  // k
  int tx = threadIdx.x, ty = threadIdx.y;
  #pragma unroll
  for (int r = 0; r < 32; r += 8)
    tile[ty + r][tx] = src[(size_t)(by + ty + r) * N + bx + tx];
  __syncthreads();
  #pragma unroll
  for (int r = 0; r < 32; r += 8)
    dst[(size_t)(bx + ty + r) * K + by + tx] = __float2bfloat16(tile[tx][ty + r]);
}

// ---------------- NT GEMM: C[M,N] = A[M,K](bf16) * Bt[N,K](bf16)^T ----------------
// EPI 0: scatter to q (B,H,S,HD), k (B,HKV,S,HD), vT (B,HKV,HD,S)   (N=3072)
// EPI 1: write fp32 C row-major (N=2048)
template <int EPI>
__global__ __launch_bounds__(256) void gemm_nt(
    const bf16* __restrict__ A, const bf16* __restrict__ Bt,
    bf16* __restrict__ Oq, bf16* __restrict__ Ok, bf16* __restrict__ Ov,
    float* __restrict__ Of, int K, int N) {
  __shared__ __align__(16) bf16 Al[128 * 72];
  __shared__ __align__(16) bf16 Bl[128 * 72];
  const int tid = threadIdx.x;
  const int lane = tid & 63, w = tid >> 6;
  const int wm = (w >> 1) * 64, wn = (w & 1) * 64;
  const int m0 = blockIdx.y * 128, n0 = blockIdx.x * 128;
  const int lr = tid >> 3, lc = (tid & 7) * 8;
  const int l16 = lane & 15, lg = lane >> 4;
  f4v acc[4][4] = {};
  for (int k0 = 0; k0 < K; k0 += 64) {
    #pragma unroll
    for (int p = 0; p < 4; ++p) {
      int r = lr + p * 32;
      *reinterpret_cast<float4*>(&Al[r * 72 + lc]) =
          *reinterpret_cast<const float4*>(&A[(size_t)(m0 + r) * K + k0 + lc]);
      *reinterpret_cast<float4*>(&Bl[r * 72 + lc]) =
          *reinterpret_cast<const float4*>(&Bt[(size_t)(n0 + r) * K + k0 + lc]);
    }
    __syncthreads();
    #pragma unroll
    for (int kc = 0; kc < 2; ++kc) {
      s8v af[4], bfr[4];
      #pragma unroll
      for (int mf = 0; mf < 4; ++mf)
        af[mf] = *reinterpret_cast<const s8v*>(&Al[(wm + mf * 16 + l16) * 72 + kc * 32 + lg * 8]);
      #pragma unroll
      for (int nf = 0; nf < 4; ++nf)
        bfr[nf] = *reinterpret_cast<const s8v*>(&Bl[(wn + nf * 16 + l16) * 72 + kc * 32 + lg * 8]);
      #pragma unroll
      for (int mf = 0; mf < 4; ++mf)
        #pragma unroll
        for (int nf = 0; nf < 4; ++nf)
          acc[mf][nf] = __builtin_amdgcn_mfma_f32_16x16x32_bf16(af[mf], bfr[nf], acc[mf][nf], 0, 0, 0);
    }
    __syncthreads();
  }
  #pragma unroll
  for (int mf = 0; mf < 4; ++mf) {
    #pragma unroll
    for (int nf = 0; nf < 4; ++nf) {
      #pragma unroll
      for (int i = 0; i < 4; ++i) {
        int gm = m0 + wm + mf * 16 + lg * 4 + i;
        int gn = n0 + wn + nf * 16 + l16;
        float v = acc[mf][nf][i];
        if (EPI == 0) {
          int b = gm >> 10, s = gm & 1023;
          if (gn < 2048) {
            int h = gn >> 7, hd = gn & 127;
            Oq[(((size_t)(b * Hn + h)) * Sn + s) * HDn + hd] = __float2bfloat16(v);
          } else if (gn < 2560) {
            int t = gn - 2048, kvh = t >> 7, hd = t & 127;
            Ok[(((size_t)(b * HKVn + kvh)) * Sn + s) * HDn + hd] = __float2bfloat16(v);
          } else {
            int t = gn - 2560, kvh = t >> 7, hd = t & 127;
            Ov[(((size_t)(b * HKVn + kvh)) * HDn + hd) * Sn + s] = __float2bfloat16(v);
          }
        } else {
          Of[(size_t)gm * N + gn] = v;
        }
      }
    }
  }
}

// ---------------- RoPE in-place on q (B,H,S,HD) and k (B,HKV,S,HD) ----------------
__global__ void rope_qk(bf16* __restrict__ qb, bf16* __restrict__ kb,
                        const float* __restrict__ cosp, const float* __restrict__ sinp) {
  const int NQ = Bn * Hn * Sn * 64;         // q pairs
  const int NT = NQ + Bn * HKVn * Sn * 64;  // + k pairs
  int stride = gridDim.x * blockDim.x;
  for (int idx = blockIdx.x * blockDim.x + threadIdx.x; idx < NT; idx += stride) {
    bf16* base;
    int rel;
    if (idx < NQ) { base = qb; rel = idx; }
    else          { base = kb; rel = idx - NQ; }
    int d = rel & 63;
    int s = (rel >> 6) & 1023;
    int head = rel >> 16;
    bf16* p = base + ((size_t)head * Sn + s) * HDn + d;
    float x1 = __bfloat162float(p[0]);
    float x2 = __bfloat162float(p[64]);
    float c = cosp[s * HDn + d];
    float sv = sinp[s * HDn + d];
    p[0]  = __float2bfloat16(x1 * c - x2 * sv);
    p[64] = __float2bfloat16(x2 * c + x1 * sv);
  }
}

// ---------------- fused flash attention (GQA, causal + active mask) ----------------
// grid: (S/64, H, B), block 256 (4 waves, 16 q-rows each)
__global__ __launch_bounds__(256) void attn_fwd(
    const bf16* __restrict__ q, const bf16* __restrict__ k, const bf16* __restrict__ vT,
    const unsigned char* __restrict__ m8, bf16* __restrict__ out) {
  __shared__ __align__(16) bf16 Pl[4][16 * 72];
  const int tid = threadIdx.x;
  const int lane = tid & 63, w = tid >> 6;
  const int l16 = lane & 15, lg = lane >> 4;
  const int qt = blockIdx.x, h = blockIdx.y, b = blockIdx.z;
  const int hkv = h >> 2;
  const int q0 = qt * 64 + w * 16;
  const float scale = 0.08838834764831845f;  // 128^-0.5

  const bf16* qp = q + ((size_t)(b * Hn + h) * Sn + q0) * HDn;
  const bf16* kp = k + (size_t)(b * HKVn + hkv) * Sn * HDn;
  const bf16* vp = vT + (size_t)(b * HKVn + hkv) * HDn * Sn;
  const unsigned char* mp = m8 + b * Sn;

  s8v qf[4];
  #pragma unroll
  for (int hc = 0; hc < 4; ++hc)
    qf[hc] = *reinterpret_cast<const s8v*>(qp + l16 * HDn + hc * 32 + lg * 8);

  float mrow[4], lrow[4];
  f4v o[8] = {};
  #pragma unroll
  for (int i = 0; i < 4; ++i) { mrow[i] = -1e30f; lrow[i] = 0.f; }

  for (int kt = 0; kt <= qt; ++kt) {
    const int kb = kt * 64;
    f4v sc[4] = {};
    #pragma unroll
    for (int ktc = 0; ktc < 4; ++ktc) {
      #pragma unroll
      for (int hc = 0; hc < 4; ++hc) {
        s8v kf = *reinterpret_cast<const s8v*>(kp + (size_t)(kb + ktc * 16 + l16) * HDn + hc * 32 + lg * 8);
        sc[ktc] = __builtin_amdgcn_mfma_f32_16x16x32_bf16(qf[hc], kf, sc[ktc], 0, 0, 0);
      }
    }
    // mask + scale + per-row max (rows live in (lg, reg i); cols in l16 x 4 tiles)
    float pm[4];
    #pragma unroll
    for (int i = 0; i < 4; ++i) pm[i] = -1e30f;
    int act[4];
    #pragma unroll
    for (int ktc = 0; ktc < 4; ++ktc) act[ktc] = mp[kb + ktc * 16 + l16];
    #pragma unroll
    for (int ktc = 0; ktc < 4; ++ktc) {
      int j = kb + ktc * 16 + l16;
      #pragma unroll
      for (int i = 0; i < 4; ++i) {
        int qr = q0 + lg * 4 + i;
        float v = sc[ktc][i] * scale;
        v = (act[ktc] && j <= qr) ? v : -1e30f;
        sc[ktc][i] = v;
        pm[i] = fmaxf(pm[i], v);
      }
    }
    #pragma unroll
    for (int off = 1; off < 16; off <<= 1)
      #pragma unroll
      for (int i = 0; i < 4; ++i) pm[i] = fmaxf(pm[i], __shfl_xor(pm[i], off, 64));
    float fac[4];
    #pragma unroll
    for (int i = 0; i < 4; ++i) {
      float mn = fmaxf(mrow[i], pm[i]);
      fac[i] = __expf(mrow[i] - mn);
      mrow[i] = mn;
    }
    float rs[4] = {0.f, 0.f, 0.f, 0.f};
    #pragma unroll
    for (int ktc = 0; ktc < 4; ++ktc)
      #pragma unroll
      for (int i = 0; i < 4; ++i) {
        float p = __expf(sc[ktc][i] - mrow[i]);
        rs[i] += p;
        Pl[w][(lg * 4 + i) * 72 + ktc * 16 + l16] = __float2bfloat16(p);
      }
    #pragma unroll
    for (int off = 1; off < 16; off <<= 1)
      #pragma unroll
      for (int i = 0; i < 4; ++i) rs[i] += __shfl_xor(rs[i], off, 64);
    #pragma unroll
    for (int i = 0; i < 4; ++i) lrow[i] = lrow[i] * fac[i] + rs[i];
    #pragma unroll
    for (int fn = 0; fn < 8; ++fn)
      #pragma unroll
      for (int i = 0; i < 4; ++i) o[fn][i] *= fac[i];
    // PV
    #pragma unroll
    for (int kc = 0; kc < 2; ++kc) {
      s8v pf = *reinterpret_cast<const s8v*>(&Pl[w][l16 * 72 + kc * 32 + lg * 8]);
      #pragma unroll
      for (int fn = 0; fn < 8; ++fn) {
        s8v vf = *reinterpret_cast<const s8v*>(vp + (size_t)(fn * 16 + l16) * Sn + kb + kc * 32 + lg * 8);
        o[fn] = __builtin_amdgcn_mfma_f32_16x16x32_bf16(pf, vf, o[fn], 0, 0, 0);
      }
    }
  }
  // write attn_out (B*S, H*HD) bf16
  #pragma unroll
  for (int fn = 0; fn < 8; ++fn)
    #pragma unroll
    for (int i = 0; i < 4; ++i) {
      int qr = q0 + lg * 4 + i;
      out[((size_t)b * Sn + qr) * (Hn * HDn) + h * HDn + fn * 16 + l16] =
          __float2bfloat16(o[fn][i] / lrow[i]);
    }
}

extern "C" void kernel_launch(void* const* d_in, const int* in_sizes, int n_in,
                              void* d_out, int out_size, void* d_ws, size_t ws_size,
                              hipStream_t stream) {
  const float* hs   = (const float*)d_in[0];
  const float* cosp = (const float*)d_in[1];
  const float* sinp = (const float*)d_in[2];
  const float* wq   = (const float*)d_in[3];
  const float* wk   = (const float*)d_in[4];
  const float* wv   = (const float*)d_in[5];
  const float* wo   = (const float*)d_in[6];
  const void*  am   = d_in[8];   // position_ids (d_in[7]) == arange, unused

  char* ws = (char*)d_ws;
  bf16* WT  = (bf16*)(ws);                         // (3072, 2048) bf16 = 12.58 MB
  bf16* woT = (bf16*)(ws + 12582912);              // (2048, 2048) bf16 = 8 MB
  bf16* qb  = (bf16*)(ws + 12582912 + 8388608);    // (B,H,S,HD)  8 MB
  bf16* kb  = (bf16*)(ws + 12582912 + 16777216);   // (B,HKV,S,HD) 2 MB
  bf16* vT  = (bf16*)(ws + 12582912 + 18874368);   // (B,HKV,HD,S) 2 MB
  bf16* ao  = (bf16*)(ws + 12582912 + 20971520);   // (B*S, 2048)  8 MB
  unsigned char* m8 = (unsigned char*)(ws + 12582912 + 29360128);
  bf16* hsb = (bf16*)d_out;                        // scratch: hs bf16 (8 MB of 16 MB out buf)
  float* outp = (float*)d_out;

  mask_norm<<<1, 256, 0, stream>>>(am, m8, Bn * Sn);
  cvt_bf16<<<2048, 256, 0, stream>>>(hs, hsb, (Bn * Sn * Dn) / 4);
  transpose_w<<<dim3(64, 64), dim3(32, 8), 0, stream>>>(wq, WT, Dn, 2048);
  transpose_w<<<dim3(16, 64), dim3(32, 8), 0, stream>>>(wk, WT + (size_t)2048 * Dn, Dn, 512);
  transpose_w<<<dim3(16, 64), dim3(32, 8), 0, stream>>>(wv, WT + (size_t)2560 * Dn, Dn, 512);
  transpose_w<<<dim3(64, 64), dim3(32, 8), 0, stream>>>(wo, woT, Dn, 2048);
  gemm_nt<0><<<dim3(24, 16), 256, 0, stream>>>(hsb, WT, qb, kb, vT, nullptr, Dn, 3072);
  rope_qk<<<2048, 256, 0, stream>>>(qb, kb, cosp, sinp);
  attn_fwd<<<dim3(Sn / 64, Hn, Bn), 256, 0, stream>>>(qb, kb, vT, m8, ao);
  gemm_nt<1><<<dim3(16, 16), 256, 0, stream>>>(ao, woT, nullptr, nullptr, nullptr, outp, Hn * HDn, Dn);
}